// Round 2
// baseline (13782.971 us; speedup 1.0000x reference)
//
#include <hip/hip_runtime.h>

#define H 1024
#define V 32000
#define NSTEP 128
#define LBLK 1000          // logits blocks
#define ROWS_PER_BLK 32
#define ROWS_PER_WAVE 8

// workspace float offsets
#define WS_H0    0         // [2][H] double buffer
#define WS_C0    2048
#define WS_H1    3072      // [2][H] double buffer
#define WS_C1    5120
#define WS_TOK   6144
#define WS_LOGZ  6400      // [NSTEP]
#define WS_PMAX  8192      // [LBLK]
#define WS_PSUM  10240     // [LBLK]
#define WS_PIDX  12288     // [LBLK] (int)
#define WS_CNT   14336     // [NSTEP] (int)

__device__ __forceinline__ float wave_dot(const float4* __restrict__ wrow4,
                                          const float4* __restrict__ v4) {
    int lane = threadIdx.x & 63;
    float acc = 0.f;
#pragma unroll
    for (int k = 0; k < 4; ++k) {
        float4 w = wrow4[lane + 64 * k];
        float4 x = v4[lane + 64 * k];
        acc += w.x * x.x + w.y * x.y + w.z * x.z + w.w * x.w;
    }
#pragma unroll
    for (int off = 32; off > 0; off >>= 1)
        acc += __shfl_down(acc, off, 64);
    return acc;  // valid in lane 0
}

__device__ __forceinline__ float sigmoidf_(float x) {
    return 1.f / (1.f + expf(-x));
}

// ---- setup: ctx = cv0*cv1 ; h = W_up@ctx + b_up ; init states, zero counters ----
__global__ __launch_bounds__(256) void k_setup(const float* __restrict__ Wup,
                                               const float* __restrict__ bup,
                                               const float* __restrict__ cv,
                                               const int* __restrict__ y,
                                               float* __restrict__ ws) {
    int r = blockIdx.x;      // 1024 blocks, one row each
    int t = threadIdx.x;
    __shared__ float red[256];
    const float* row = Wup + (size_t)r * H;
    float acc = 0.f;
    for (int j = t; j < H; j += 256) acc += row[j] * (cv[j] * cv[H + j]);
    red[t] = acc;
    __syncthreads();
    for (int s = 128; s > 0; s >>= 1) {
        if (t < s) red[t] += red[t + s];
        __syncthreads();
    }
    if (r == 0 && t < NSTEP) ((int*)ws)[WS_CNT + t] = 0;   // zero step counters
    if (t == 0) {
        float h = red[0] + bup[r];
        ws[WS_H0 + r] = h;
        ws[WS_C0 + r] = h;
        ws[WS_H1 + r] = h;
        ws[WS_C1 + r] = h;
        if (r == 0) ws[WS_TOK] = (float)y[0];
    }
}

// ---- LSTM layer 0: input is scalar token ----
__global__ __launch_bounds__(256) void k_lstm0(const float* __restrict__ Whh,
                                               const float* __restrict__ Wih_col,
                                               const float* __restrict__ bih,
                                               const float* __restrict__ bhh,
                                               float* __restrict__ ws, int par) {
    __shared__ float4 shv[256];
    __shared__ float gates[4];
    int i = blockIdx.x;   // cell index, 1024 blocks
    int t = threadIdx.x;
    const float* hin = ws + WS_H0 + par * H;
    shv[t] = ((const float4*)hin)[t];
    __syncthreads();
    int w = t >> 6;
    int r = i + (w << 10);
    float d = wave_dot((const float4*)(Whh + (size_t)r * H), shv);
    if ((t & 63) == 0) {
        float tok = ws[WS_TOK];
        gates[w] = d + Wih_col[r] * tok + bih[r] + bhh[r];
    }
    __syncthreads();
    if (t == 0) {
        float ig = sigmoidf_(gates[0]);
        float fg = sigmoidf_(gates[1]);
        float gg = tanhf(gates[2]);
        float og = sigmoidf_(gates[3]);
        float c = fg * ws[WS_C0 + i] + ig * gg;
        ws[WS_C0 + i] = c;
        ws[WS_H0 + (par ^ 1) * H + i] = og * tanhf(c);
    }
}

// ---- LSTM layer 1: input is new h0 ----
__global__ __launch_bounds__(256) void k_lstm1(const float* __restrict__ Wih,
                                               const float* __restrict__ Whh,
                                               const float* __restrict__ bih,
                                               const float* __restrict__ bhh,
                                               float* __restrict__ ws, int par) {
    __shared__ float4 shx[256];
    __shared__ float4 shh[256];
    __shared__ float gates[4];
    int i = blockIdx.x;
    int t = threadIdx.x;
    shx[t] = ((const float4*)(ws + WS_H0 + (par ^ 1) * H))[t];
    shh[t] = ((const float4*)(ws + WS_H1 + par * H))[t];
    __syncthreads();
    int w = t >> 6;
    int r = i + (w << 10);
    float d = wave_dot((const float4*)(Wih + (size_t)r * H), shx) +
              wave_dot((const float4*)(Whh + (size_t)r * H), shh);
    if ((t & 63) == 0) gates[w] = d + bih[r] + bhh[r];
    __syncthreads();
    if (t == 0) {
        float ig = sigmoidf_(gates[0]);
        float fg = sigmoidf_(gates[1]);
        float gg = tanhf(gates[2]);
        float og = sigmoidf_(gates[3]);
        float c = fg * ws[WS_C1 + i] + ig * gg;
        ws[WS_C1 + i] = c;
        ws[WS_H1 + (par ^ 1) * H + i] = og * tanhf(c);
    }
}

// ---- logits + fused reduction (last-block): relu(W_out@h1+b) -> out row;
//      last arriving block computes logZ[step] and next token ----
__global__ __launch_bounds__(256) void k_logits(const float* __restrict__ Wout,
                                                const float* __restrict__ bout,
                                                float* __restrict__ outrow,
                                                float* __restrict__ ws,
                                                int par, int step) {
    __shared__ float4 shv[256];
    __shared__ float wmax[4], wsum[4];
    __shared__ int widx[4];
    __shared__ int lastflag;
    __shared__ float rm[256], rs[256];
    __shared__ int ri[256];
    int b = blockIdx.x;
    int t = threadIdx.x;
    int w = t >> 6, lane = t & 63;
    shv[t] = ((const float4*)(ws + WS_H1 + (par ^ 1) * H))[t];
    __syncthreads();
    float m = -1e30f, s = 0.f;
    int mi = 0;
    int rbase = b * ROWS_PER_BLK + w * ROWS_PER_WAVE;
#pragma unroll
    for (int k = 0; k < ROWS_PER_WAVE; ++k) {
        int r = rbase + k;
        float d = wave_dot((const float4*)(Wout + (size_t)r * H), shv);
        if (lane == 0) {
            float v = fmaxf(d + bout[r], 0.f);   // relu
            outrow[r] = v;
            if (v > m) { s = s * expf(m - v) + 1.f; m = v; mi = r; }
            else       { s += expf(v - m); }
        }
    }
    if (lane == 0) { wmax[w] = m; wsum[w] = s; widx[w] = mi; }
    __syncthreads();
    if (t == 0) {
        float bm = wmax[0], bs = wsum[0];
        int bi = widx[0];
#pragma unroll
        for (int k = 1; k < 4; ++k) {
            float m2 = wmax[k], s2 = wsum[k];
            int i2 = widx[k];
            if (m2 > bm)      { bs = bs * expf(bm - m2) + s2; bm = m2; bi = i2; }
            else if (m2 == bm){ bs += s2; if (i2 < bi) bi = i2; }
            else              { bs += s2 * expf(m2 - bm); }
        }
        __hip_atomic_store(ws + WS_PMAX + b, bm, __ATOMIC_RELEASE, __HIP_MEMORY_SCOPE_AGENT);
        __hip_atomic_store(ws + WS_PSUM + b, bs, __ATOMIC_RELEASE, __HIP_MEMORY_SCOPE_AGENT);
        __hip_atomic_store((int*)ws + WS_PIDX + b, bi, __ATOMIC_RELEASE, __HIP_MEMORY_SCOPE_AGENT);
        int old = __hip_atomic_fetch_add((int*)ws + WS_CNT + step, 1,
                                         __ATOMIC_ACQ_REL, __HIP_MEMORY_SCOPE_AGENT);
        lastflag = (old == LBLK - 1);
    }
    __syncthreads();
    if (!lastflag) return;
    // final reduce over LBLK partials
    float fm = -1e30f, fs = 0.f;
    int fi = 0x7fffffff;
    for (int i = t; i < LBLK; i += 256) {
        float m2 = __hip_atomic_load(ws + WS_PMAX + i, __ATOMIC_ACQUIRE, __HIP_MEMORY_SCOPE_AGENT);
        float s2 = __hip_atomic_load(ws + WS_PSUM + i, __ATOMIC_ACQUIRE, __HIP_MEMORY_SCOPE_AGENT);
        int i2 = __hip_atomic_load((int*)ws + WS_PIDX + i, __ATOMIC_ACQUIRE, __HIP_MEMORY_SCOPE_AGENT);
        if (m2 > fm)       { fs = fs * expf(fm - m2) + s2; fm = m2; fi = i2; }
        else if (m2 == fm) { fs += s2; if (i2 < fi) fi = i2; }
        else               { fs += s2 * expf(m2 - fm); }
    }
    rm[t] = fm; rs[t] = fs; ri[t] = fi;
    __syncthreads();
    for (int o = 128; o > 0; o >>= 1) {
        if (t < o) {
            float m2 = rm[t + o], s2 = rs[t + o];
            int i2 = ri[t + o];
            if (m2 > rm[t])       { rs[t] = rs[t] * expf(rm[t] - m2) + s2; rm[t] = m2; ri[t] = i2; }
            else if (m2 == rm[t]) { rs[t] += s2; if (i2 < ri[t]) ri[t] = i2; }
            else                  { rs[t] += s2 * expf(m2 - rm[t]); }
        }
        __syncthreads();
    }
    if (t == 0) {
        ws[WS_LOGZ + step] = rm[0] + logf(rs[0]);
        ws[WS_TOK] = (float)ri[0];
    }
}

// ---- final: subtract logZ[row] from every output element ----
__global__ __launch_bounds__(256) void k_norm_all(float* __restrict__ out,
                                                  const float* __restrict__ ws) {
    int stride = gridDim.x * 256;
    for (int i = blockIdx.x * 256 + threadIdx.x; i < NSTEP * V; i += stride)
        out[i] -= ws[WS_LOGZ + i / V];
}

extern "C" void kernel_launch(void* const* d_in, const int* in_sizes, int n_in,
                              void* d_out, int out_size, void* d_ws, size_t ws_size,
                              hipStream_t stream) {
    const int*   y    = (const int*)d_in[0];
    const float* cv   = (const float*)d_in[1];
    const float* Wup  = (const float*)d_in[3];
    const float* bup  = (const float*)d_in[4];
    const float* Wih0 = (const float*)d_in[5];   // [4096,1] column
    const float* Whh0 = (const float*)d_in[6];
    const float* bih0 = (const float*)d_in[7];
    const float* bhh0 = (const float*)d_in[8];
    const float* Wih1 = (const float*)d_in[9];
    const float* Whh1 = (const float*)d_in[10];
    const float* bih1 = (const float*)d_in[11];
    const float* bhh1 = (const float*)d_in[12];
    const float* Wout = (const float*)d_in[13];
    const float* bout = (const float*)d_in[14];
    float* out = (float*)d_out;
    float* ws  = (float*)d_ws;

    k_setup<<<1024, 256, 0, stream>>>(Wup, bup, cv, y, ws);
    for (int t = 0; t < NSTEP; ++t) {
        int par = t & 1;
        k_lstm0<<<1024, 256, 0, stream>>>(Whh0, Wih0, bih0, bhh0, ws, par);
        k_lstm1<<<1024, 256, 0, stream>>>(Wih1, Whh1, bih1, bhh1, ws, par);
        k_logits<<<LBLK, 256, 0, stream>>>(Wout, bout, out + (size_t)t * V, ws, par, t);
    }
    k_norm_all<<<2048, 256, 0, stream>>>(out, ws);
}

// Round 4
// 13343.250 us; speedup vs baseline: 1.0330x; 1.0330x over previous
//
#include <hip/hip_runtime.h>
#include <hip/hip_cooperative_groups.h>

namespace cg = cooperative_groups;

#define H 1024
#define V 32000
#define NSTEP 128
#define NBLK 256
#define NTHR 512
#define RPB 125          // logits rows per block = V/NBLK

// cooperative-path ws float offsets
#define WS_H0   0        // [2][H]
#define WS_C0   2048     // [H]
#define WS_H1   3072     // [2][H]
#define WS_C1   5120     // [H]
#define WS_LOGZ 6144     // [NSTEP]
#define WS_PM   6400     // [NBLK]
#define WS_PS   6656     // [NBLK]
#define WS_PI   6912     // [NBLK] (int)

__device__ __forceinline__ float sigmoidf_(float x) { return 1.f / (1.f + expf(-x)); }

__device__ __forceinline__ float wred(float a) {
#pragma unroll
    for (int o = 32; o > 0; o >>= 1) a += __shfl_down(a, o, 64);
    return a;   // valid in lane 0
}

// dot of one 1024-elem weight row with h held in 4 float4 regs (lane-sliced)
__device__ __forceinline__ float dot_row(const float4* __restrict__ w4,
                                         const float4* h, int lane) {
    float a = 0.f;
#pragma unroll
    for (int k = 0; k < 4; ++k) {
        float4 w = w4[lane + (k << 6)];
        a += w.x * h[k].x + w.y * h[k].y + w.z * h[k].z + w.w * h[k].w;
    }
    return a;
}

__global__ __launch_bounds__(NTHR) void k_decoder(
    const int* __restrict__ y, const float* __restrict__ cv,
    const float* __restrict__ Wup, const float* __restrict__ bup,
    const float* __restrict__ Wih0, const float* __restrict__ Whh0,
    const float* __restrict__ bih0, const float* __restrict__ bhh0,
    const float* __restrict__ Wih1, const float* __restrict__ Whh1,
    const float* __restrict__ bih1, const float* __restrict__ bhh1,
    const float* __restrict__ Wout, const float* __restrict__ bout,
    float* __restrict__ out, float* __restrict__ ws)
{
    cg::grid_group grid = cg::this_grid();
    const int b = blockIdx.x, t = threadIdx.x;
    const int w = t >> 6, lane = t & 63;
    const int gw = (b << 3) + w;          // global wave id, 0..2047

    __shared__ float gl[4][4];            // [cell-in-block][gate i,f,g,o]
    __shared__ float pm[8], psv[8];
    __shared__ int   pix[8];
    __shared__ float rm[NBLK], rs[NBLK];
    __shared__ int   ri[NBLK];
    __shared__ float s_tok;

    // ---- init: h = Wup @ (cv0*cv1) + bup ; replicate into h0/c0/h1/c1 ----
    if (gw < 1024) {
        float4 hreg[4];
#pragma unroll
        for (int k = 0; k < 4; ++k) {
            float4 a = ((const float4*)cv)[lane + (k << 6)];
            float4 c = ((const float4*)(cv + H))[lane + (k << 6)];
            hreg[k] = make_float4(a.x * c.x, a.y * c.y, a.z * c.z, a.w * c.w);
        }
        float acc = wred(dot_row((const float4*)(Wup + (size_t)gw * H), hreg, lane));
        if (lane == 0) {
            float h = acc + bup[gw];
            ws[WS_H0 + gw] = h; ws[WS_C0 + gw] = h;
            ws[WS_H1 + gw] = h; ws[WS_C1 + gw] = h;
        }
    }
    grid.sync();

    for (int step = 0; step < NSTEP; ++step) {
        const int p = step & 1;

        // ---- D: every block redundantly reduces prev-step partials -> tok ----
        float tok;
        if (step == 0) {
            tok = (float)y[0];
        } else {
            if (t < NBLK) { rm[t] = ws[WS_PM + t]; rs[t] = ws[WS_PS + t]; ri[t] = ((const int*)ws)[WS_PI + t]; }
            __syncthreads();
            for (int o = NBLK >> 1; o > 0; o >>= 1) {
                if (t < o) {
                    float m2 = rm[t + o], s2 = rs[t + o];
                    int i2 = ri[t + o];
                    if (m2 > rm[t])       { rs[t] = rs[t] * expf(rm[t] - m2) + s2; rm[t] = m2; ri[t] = i2; }
                    else if (m2 == rm[t]) { rs[t] += s2; if (i2 < ri[t]) ri[t] = i2; }
                    else                  { rs[t] += s2 * expf(m2 - rm[t]); }
                }
                __syncthreads();
            }
            if (t == 0) {
                s_tok = (float)ri[0];
                if (b == 0) ws[WS_LOGZ + step - 1] = rm[0] + logf(rs[0]);
            }
            __syncthreads();
            tok = s_tok;
        }

        // ---- A: lstm0 (cells 4b..4b+3; wave pair per cell) ----
        {
            const float4* h0o = (const float4*)(ws + WS_H0 + p * H);
            float4 hreg[4];
#pragma unroll
            for (int k = 0; k < 4; ++k) hreg[k] = h0o[lane + (k << 6)];
            const int cell = (b << 2) + (w >> 1);
            const int r0 = cell + ((w & 1) << 11);   // i-or-g row
            const int r1 = r0 + 1024;                // f-or-o row
            float a0 = dot_row((const float4*)(Whh0 + (size_t)r0 * H), hreg, lane);
            float a1 = dot_row((const float4*)(Whh0 + (size_t)r1 * H), hreg, lane);
            a0 = wred(a0); a1 = wred(a1);
            if (lane == 0) {
                int gi = (w & 1) << 1;
                gl[w >> 1][gi]     = a0 + Wih0[r0] * tok + bih0[r0] + bhh0[r0];
                gl[w >> 1][gi + 1] = a1 + Wih0[r1] * tok + bih0[r1] + bhh0[r1];
            }
            __syncthreads();
            if (t < 4) {
                int c = (b << 2) + t;
                float ig = sigmoidf_(gl[t][0]);
                float fg = sigmoidf_(gl[t][1]);
                float gg = tanhf(gl[t][2]);
                float og = sigmoidf_(gl[t][3]);
                float cc = fg * ws[WS_C0 + c] + ig * gg;
                ws[WS_C0 + c] = cc;
                ws[WS_H0 + (p ^ 1) * H + c] = og * tanhf(cc);
            }
        }
        grid.sync();

        // ---- B: lstm1 ----
        {
            const float4* h0n = (const float4*)(ws + WS_H0 + (p ^ 1) * H);
            const float4* h1o = (const float4*)(ws + WS_H1 + p * H);
            float4 hx[4], hh[4];
#pragma unroll
            for (int k = 0; k < 4; ++k) { hx[k] = h0n[lane + (k << 6)]; hh[k] = h1o[lane + (k << 6)]; }
            const int cell = (b << 2) + (w >> 1);
            const int r0 = cell + ((w & 1) << 11);
            const int r1 = r0 + 1024;
            float a0 = dot_row((const float4*)(Wih1 + (size_t)r0 * H), hx, lane)
                     + dot_row((const float4*)(Whh1 + (size_t)r0 * H), hh, lane);
            float a1 = dot_row((const float4*)(Wih1 + (size_t)r1 * H), hx, lane)
                     + dot_row((const float4*)(Whh1 + (size_t)r1 * H), hh, lane);
            a0 = wred(a0); a1 = wred(a1);
            if (lane == 0) {
                int gi = (w & 1) << 1;
                gl[w >> 1][gi]     = a0 + bih1[r0] + bhh1[r0];
                gl[w >> 1][gi + 1] = a1 + bih1[r1] + bhh1[r1];
            }
            __syncthreads();
            if (t < 4) {
                int c = (b << 2) + t;
                float ig = sigmoidf_(gl[t][0]);
                float fg = sigmoidf_(gl[t][1]);
                float gg = tanhf(gl[t][2]);
                float og = sigmoidf_(gl[t][3]);
                float cc = fg * ws[WS_C1 + c] + ig * gg;
                ws[WS_C1 + c] = cc;
                ws[WS_H1 + (p ^ 1) * H + c] = og * tanhf(cc);
            }
        }
        grid.sync();

        // ---- C: logits + per-block softmax partial ----
        {
            const float4* h1n = (const float4*)(ws + WS_H1 + (p ^ 1) * H);
            float4 hreg[4];
#pragma unroll
            for (int k = 0; k < 4; ++k) hreg[k] = h1n[lane + (k << 6)];
            float* orow = out + (size_t)step * V;
            const int rbase = b * RPB;
            int rl = w << 4;
            const int rend = (w == 7) ? RPB : (rl + 16);
            float m = -1e30f, s = 0.f;
            int mi = 0x7fffffff;
            for (; rl + 1 < rend; rl += 2) {
                int r = rbase + rl;
                float a0 = dot_row((const float4*)(Wout + (size_t)r * H), hreg, lane);
                float a1 = dot_row((const float4*)(Wout + (size_t)(r + 1) * H), hreg, lane);
                a0 = wred(a0); a1 = wred(a1);
                if (lane == 0) {
                    float v0 = fmaxf(a0 + bout[r], 0.f);
                    float v1 = fmaxf(a1 + bout[r + 1], 0.f);
                    orow[r] = v0; orow[r + 1] = v1;
                    if (v0 > m) { s = s * expf(m - v0) + 1.f; m = v0; mi = r; }     else s += expf(v0 - m);
                    if (v1 > m) { s = s * expf(m - v1) + 1.f; m = v1; mi = r + 1; } else s += expf(v1 - m);
                }
            }
            if (rl < rend) {
                int r = rbase + rl;
                float a0 = wred(dot_row((const float4*)(Wout + (size_t)r * H), hreg, lane));
                if (lane == 0) {
                    float v0 = fmaxf(a0 + bout[r], 0.f);
                    orow[r] = v0;
                    if (v0 > m) { s = s * expf(m - v0) + 1.f; m = v0; mi = r; } else s += expf(v0 - m);
                }
            }
            if (lane == 0) { pm[w] = m; psv[w] = s; pix[w] = mi; }
            __syncthreads();
            if (t == 0) {
                float bm = pm[0], bs = psv[0];
                int bi = pix[0];
#pragma unroll
                for (int k = 1; k < 8; ++k) {
                    float m2 = pm[k], s2 = psv[k];
                    int i2 = pix[k];
                    if (m2 > bm)       { bs = bs * expf(bm - m2) + s2; bm = m2; bi = i2; }
                    else if (m2 == bm) { bs += s2; if (i2 < bi) bi = i2; }
                    else               { bs += s2 * expf(m2 - bm); }
                }
                ws[WS_PM + b] = bm; ws[WS_PS + b] = bs; ((int*)ws)[WS_PI + b] = bi;
            }
        }
        grid.sync();
    }

    // ---- final logZ[127] ----
    if (t < NBLK) { rm[t] = ws[WS_PM + t]; rs[t] = ws[WS_PS + t]; }
    __syncthreads();
    for (int o = NBLK >> 1; o > 0; o >>= 1) {
        if (t < o) {
            float m2 = rm[t + o], s2 = rs[t + o];
            if (m2 > rm[t])       { rs[t] = rs[t] * expf(rm[t] - m2) + s2; rm[t] = m2; }
            else if (m2 == rm[t]) { rs[t] += s2; }
            else                  { rs[t] += s2 * expf(m2 - rm[t]); }
        }
        __syncthreads();
    }
    if (b == 0 && t == 0) ws[WS_LOGZ + NSTEP - 1] = rm[0] + logf(rs[0]);
    grid.sync();

    // ---- normalize all rows ----
    for (int i = b * NTHR + t; i < NSTEP * V; i += NBLK * NTHR)
        out[i] -= ws[WS_LOGZ + i / V];
}

// ======================= fallback path (round-1 proven) =======================
#define F_NLB 8000
#define F_H0    0
#define F_C0    2048
#define F_H1    3072
#define F_C1    5120
#define F_TOK   6144
#define F_LOGZ  6145
#define F_PMAX  8192
#define F_PSUM  16384
#define F_PIDX  24576

__device__ __forceinline__ float wave_dot_s(const float4* __restrict__ wrow4,
                                            const float4* __restrict__ v4) {
    int lane = threadIdx.x & 63;
    float acc = 0.f;
#pragma unroll
    for (int k = 0; k < 4; ++k) {
        float4 w = wrow4[lane + 64 * k];
        float4 x = v4[lane + 64 * k];
        acc += w.x * x.x + w.y * x.y + w.z * x.z + w.w * x.w;
    }
#pragma unroll
    for (int off = 32; off > 0; off >>= 1) acc += __shfl_down(acc, off, 64);
    return acc;
}

__global__ __launch_bounds__(256) void f_setup(const float* __restrict__ Wup,
                                               const float* __restrict__ bup,
                                               const float* __restrict__ cv,
                                               const int* __restrict__ y,
                                               float* __restrict__ ws) {
    int r = blockIdx.x, t = threadIdx.x;
    __shared__ float red[256];
    const float* row = Wup + (size_t)r * H;
    float acc = 0.f;
    for (int j = t; j < H; j += 256) acc += row[j] * (cv[j] * cv[H + j]);
    red[t] = acc;
    __syncthreads();
    for (int s = 128; s > 0; s >>= 1) { if (t < s) red[t] += red[t + s]; __syncthreads(); }
    if (t == 0) {
        float h = red[0] + bup[r];
        ws[F_H0 + r] = h; ws[F_C0 + r] = h; ws[F_H1 + r] = h; ws[F_C1 + r] = h;
        if (r == 0) ws[F_TOK] = (float)y[0];
    }
}

__global__ __launch_bounds__(256) void f_lstm0(const float* __restrict__ Whh,
                                               const float* __restrict__ Wih_col,
                                               const float* __restrict__ bih,
                                               const float* __restrict__ bhh,
                                               float* __restrict__ ws, int par) {
    __shared__ float4 shv[256];
    __shared__ float gates[4];
    int i = blockIdx.x, t = threadIdx.x;
    shv[t] = ((const float4*)(ws + F_H0 + par * H))[t];
    __syncthreads();
    int w = t >> 6, r = i + (w << 10);
    float d = wave_dot_s((const float4*)(Whh + (size_t)r * H), shv);
    if ((t & 63) == 0) gates[w] = d + Wih_col[r] * ws[F_TOK] + bih[r] + bhh[r];
    __syncthreads();
    if (t == 0) {
        float ig = sigmoidf_(gates[0]), fg = sigmoidf_(gates[1]);
        float gg = tanhf(gates[2]), og = sigmoidf_(gates[3]);
        float c = fg * ws[F_C0 + i] + ig * gg;
        ws[F_C0 + i] = c;
        ws[F_H0 + (par ^ 1) * H + i] = og * tanhf(c);
    }
}

__global__ __launch_bounds__(256) void f_lstm1(const float* __restrict__ Wih,
                                               const float* __restrict__ Whh,
                                               const float* __restrict__ bih,
                                               const float* __restrict__ bhh,
                                               float* __restrict__ ws, int par) {
    __shared__ float4 shx[256], shh[256];
    __shared__ float gates[4];
    int i = blockIdx.x, t = threadIdx.x;
    shx[t] = ((const float4*)(ws + F_H0 + (par ^ 1) * H))[t];
    shh[t] = ((const float4*)(ws + F_H1 + par * H))[t];
    __syncthreads();
    int w = t >> 6, r = i + (w << 10);
    float d = wave_dot_s((const float4*)(Wih + (size_t)r * H), shx) +
              wave_dot_s((const float4*)(Whh + (size_t)r * H), shh);
    if ((t & 63) == 0) gates[w] = d + bih[r] + bhh[r];
    __syncthreads();
    if (t == 0) {
        float ig = sigmoidf_(gates[0]), fg = sigmoidf_(gates[1]);
        float gg = tanhf(gates[2]), og = sigmoidf_(gates[3]);
        float c = fg * ws[F_C1 + i] + ig * gg;
        ws[F_C1 + i] = c;
        ws[F_H1 + (par ^ 1) * H + i] = og * tanhf(c);
    }
}

__global__ __launch_bounds__(256) void f_logits(const float* __restrict__ Wout,
                                                const float* __restrict__ bout,
                                                float* __restrict__ outrow,
                                                float* __restrict__ ws, int par) {
    __shared__ float4 shv[256];
    __shared__ float sval[4];
    int b = blockIdx.x, t = threadIdx.x;
    shv[t] = ((const float4*)(ws + F_H1 + (par ^ 1) * H))[t];
    __syncthreads();
    int w = t >> 6, r = b * 4 + w;
    float d = wave_dot_s((const float4*)(Wout + (size_t)r * H), shv);
    if ((t & 63) == 0) {
        float v = fmaxf(d + bout[r], 0.f);
        outrow[r] = v;
        sval[w] = v;
    }
    __syncthreads();
    if (t == 0) {
        float m = sval[0]; int mi = 0;
#pragma unroll
        for (int k = 1; k < 4; ++k) if (sval[k] > m) { m = sval[k]; mi = k; }
        float s = 0.f;
#pragma unroll
        for (int k = 0; k < 4; ++k) s += expf(sval[k] - m);
        ws[F_PMAX + b] = m; ws[F_PSUM + b] = s; ((int*)ws)[F_PIDX + b] = b * 4 + mi;
    }
}

__global__ __launch_bounds__(1024) void f_reduce(float* __restrict__ ws) {
    __shared__ float sm[1024], ssum[1024];
    __shared__ int si[1024];
    int t = threadIdx.x;
    float m = -1e30f, s = 0.f;
    int idx = 0x7fffffff;
    for (int b = t; b < F_NLB; b += 1024) {
        float bm = ws[F_PMAX + b], bs = ws[F_PSUM + b];
        int bi = ((int*)ws)[F_PIDX + b];
        if (bm > m)      { s = s * expf(m - bm) + bs; m = bm; idx = bi; }
        else if (bm == m){ s += bs; if (bi < idx) idx = bi; }
        else             { s += bs * expf(bm - m); }
    }
    sm[t] = m; ssum[t] = s; si[t] = idx;
    __syncthreads();
    for (int o = 512; o > 0; o >>= 1) {
        if (t < o) {
            float m2 = sm[t + o], s2 = ssum[t + o];
            int i2 = si[t + o];
            if (m2 > sm[t])       { ssum[t] = ssum[t] * expf(sm[t] - m2) + s2; sm[t] = m2; si[t] = i2; }
            else if (m2 == sm[t]) { ssum[t] += s2; if (i2 < si[t]) si[t] = i2; }
            else                  { ssum[t] += s2 * expf(m2 - sm[t]); }
        }
        __syncthreads();
    }
    if (t == 0) { ws[F_LOGZ] = sm[0] + logf(ssum[0]); ws[F_TOK] = (float)si[0]; }
}

__global__ __launch_bounds__(256) void f_norm(float* __restrict__ outrow,
                                              const float* __restrict__ ws) {
    int i = blockIdx.x * 256 + threadIdx.x;
    if (i < V) outrow[i] -= ws[F_LOGZ];
}

extern "C" void kernel_launch(void* const* d_in, const int* in_sizes, int n_in,
                              void* d_out, int out_size, void* d_ws, size_t ws_size,
                              hipStream_t stream) {
    const int*   y    = (const int*)d_in[0];
    const float* cv   = (const float*)d_in[1];
    const float* Wup  = (const float*)d_in[3];
    const float* bup  = (const float*)d_in[4];
    const float* Wih0 = (const float*)d_in[5];
    const float* Whh0 = (const float*)d_in[6];
    const float* bih0 = (const float*)d_in[7];
    const float* bhh0 = (const float*)d_in[8];
    const float* Wih1 = (const float*)d_in[9];
    const float* Whh1 = (const float*)d_in[10];
    const float* bih1 = (const float*)d_in[11];
    const float* bhh1 = (const float*)d_in[12];
    const float* Wout = (const float*)d_in[13];
    const float* bout = (const float*)d_in[14];
    float* out = (float*)d_out;
    float* ws  = (float*)d_ws;

    void* args[] = {
        (void*)&y, (void*)&cv, (void*)&Wup, (void*)&bup,
        (void*)&Wih0, (void*)&Whh0, (void*)&bih0, (void*)&bhh0,
        (void*)&Wih1, (void*)&Whh1, (void*)&bih1, (void*)&bhh1,
        (void*)&Wout, (void*)&bout, (void*)&out, (void*)&ws
    };
    hipError_t err = hipLaunchCooperativeKernel((void*)k_decoder, dim3(NBLK), dim3(NTHR),
                                                args, 0, stream);
    if (err != hipSuccess) {
        // proven round-1 multi-kernel fallback
        f_setup<<<1024, 256, 0, stream>>>(Wup, bup, cv, y, ws);
        for (int t = 0; t < NSTEP; ++t) {
            int par = t & 1;
            f_lstm0<<<1024, 256, 0, stream>>>(Whh0, Wih0, bih0, bhh0, ws, par);
            f_lstm1<<<1024, 256, 0, stream>>>(Wih1, Whh1, bih1, bhh1, ws, par);
            f_logits<<<F_NLB, 256, 0, stream>>>(Wout, bout, out + (size_t)t * V, ws, par);
            f_reduce<<<1, 1024, 0, stream>>>(ws);
            f_norm<<<125, 256, 0, stream>>>(out + (size_t)t * V, ws);
        }
    }
}

// Round 12
// 4816.415 us; speedup vs baseline: 2.8617x; 2.7704x over previous
//
#include <hip/hip_runtime.h>

#define H 1024
#define V 32000
#define NSTEP 128
#define LBLK 2000        // logits blocks
#define LROWS 16         // rows per logits block
#define NBLK_L 256       // fused LSTM kernel blocks
#define NTHR_L 512

// ws float offsets
#define WS_G0    0        // [2][4096]  gate preact (Whh0@h0 + bih0 + bhh0), parity
#define WS_HINIT 8192     // [1024]
#define WS_C0    9216     // [2][1024]  parity
#define WS_H1    11264    // [2][1024]  parity
#define WS_C1    13312    // [1024]     block-owned
#define WS_PMAX  14336    // [LBLK]
#define WS_PIDX  16384    // [LBLK] (int)

__device__ __forceinline__ float sigmoidf_(float x) { return 1.f / (1.f + expf(-x)); }

__device__ __forceinline__ float wred(float a) {
#pragma unroll
    for (int o = 32; o > 0; o >>= 1) a += __shfl_down(a, o, 64);
    return a;   // valid in lane 0
}

// dot of one 1024-elem weight row with vector held in 4 float4 regs (lane-sliced)
__device__ __forceinline__ float dot_row(const float4* __restrict__ w4,
                                         const float4* h, int lane) {
    float a = 0.f;
#pragma unroll
    for (int k = 0; k < 4; ++k) {
        float4 w = w4[lane + (k << 6)];
        a += w.x * h[k].x + w.y * h[k].y + w.z * h[k].z + w.w * h[k].w;
    }
    return a;
}

// ---- setup: h_init = Wup @ (cv0*cv1) + bup ; init state ----
__global__ __launch_bounds__(256) void k_setup(const float* __restrict__ Wup,
                                               const float* __restrict__ bup,
                                               const float* __restrict__ cv,
                                               float* __restrict__ ws) {
    int r = blockIdx.x, t = threadIdx.x;   // 1024 blocks
    __shared__ float red[256];
    const float* row = Wup + (size_t)r * H;
    float acc = 0.f;
    for (int j = t; j < H; j += 256) acc += row[j] * (cv[j] * cv[H + j]);
    red[t] = acc;
    __syncthreads();
    for (int s = 128; s > 0; s >>= 1) { if (t < s) red[t] += red[t + s]; __syncthreads(); }
    if (t == 0) {
        float h = red[0] + bup[r];
        ws[WS_HINIT + r] = h;
        ws[WS_C0 + r] = h;       // parity 0
        ws[WS_H1 + r] = h;       // parity 0
        ws[WS_C1 + r] = h;
    }
}

// ---- G0(0) = Whh0 @ h_init + bih0 + bhh0 ----
__global__ __launch_bounds__(256) void k_g0(const float* __restrict__ Whh0,
                                            const float* __restrict__ bih0,
                                            const float* __restrict__ bhh0,
                                            float* __restrict__ ws) {
    int b = blockIdx.x, t = threadIdx.x;   // 1024 blocks, 4 waves, 1 row/wave
    int w = t >> 6, lane = t & 63;
    float4 hreg[4];
#pragma unroll
    for (int k = 0; k < 4; ++k) hreg[k] = ((const float4*)(ws + WS_HINIT))[lane + (k << 6)];
    int r = (b << 2) + w;
    float a = wred(dot_row((const float4*)(Whh0 + (size_t)r * H), hreg, lane));
    if (lane == 0) ws[WS_G0 + r] = a + bih0[r] + bhh0[r];   // parity 0
}

// ---- fused: argmax(prev partials) -> tok ; lstm0-finish (redundant) ;
//      lstm1 matvec (4 cells/block) ; G0(next) rows ----
__global__ __launch_bounds__(NTHR_L) void k_L(
    const int* __restrict__ y,
    const float* __restrict__ Wih0col,
    const float* __restrict__ Whh0,
    const float* __restrict__ bih0, const float* __restrict__ bhh0,
    const float* __restrict__ Wih1, const float* __restrict__ Whh1,
    const float* __restrict__ bih1, const float* __restrict__ bhh1,
    float* __restrict__ ws, int step)
{
    const int b = blockIdx.x, t = threadIdx.x;
    const int w = t >> 6, lane = t & 63;
    const int p = step & 1;
    __shared__ float h0s[H];
    __shared__ float rm[NTHR_L];
    __shared__ int   ri[NTHR_L];
    __shared__ float gl[4][4];

    // ---- phase 1a: token from prev-step partials (redundant per block) ----
    float tok;
    if (step == 0) {
        tok = (float)y[0];
    } else {
        float m = -1e30f;
        int idx = 0x7fffffff;
        for (int i = t; i < LBLK; i += NTHR_L) {
            float m2 = ws[WS_PMAX + i];
            int i2 = ((const int*)ws)[WS_PIDX + i];
            if (m2 > m || (m2 == m && i2 < idx)) {
                if (m2 > m) { m = m2; idx = i2; }
                else if (i2 < idx) idx = i2;
            }
        }
        rm[t] = m; ri[t] = idx;
        __syncthreads();
        for (int o = NTHR_L >> 1; o > 0; o >>= 1) {
            if (t < o) {
                float m2 = rm[t + o]; int i2 = ri[t + o];
                if (m2 > rm[t]) { rm[t] = m2; ri[t] = i2; }
                else if (m2 == rm[t] && i2 < ri[t]) ri[t] = i2;
            }
            __syncthreads();
        }
        tok = (float)ri[0];
    }

    // ---- phase 1b: finish lstm0 redundantly; h0_new -> LDS; c0 parity flip ----
    for (int c = t; c < H; c += NTHR_L) {
        float gi = ws[WS_G0 + p * 4096 + c]        + Wih0col[c]        * tok;
        float gf = ws[WS_G0 + p * 4096 + 1024 + c] + Wih0col[1024 + c] * tok;
        float gg = ws[WS_G0 + p * 4096 + 2048 + c] + Wih0col[2048 + c] * tok;
        float go = ws[WS_G0 + p * 4096 + 3072 + c] + Wih0col[3072 + c] * tok;
        float cc = sigmoidf_(gf) * ws[WS_C0 + p * H + c] + sigmoidf_(gi) * tanhf(gg);
        ws[WS_C0 + (p ^ 1) * H + c] = cc;          // identical values from all blocks
        h0s[c] = sigmoidf_(go) * tanhf(cc);
    }
    __syncthreads();

    // ---- phase 2: lstm1 matvec + G0(next) ----
    float4 hx[4], hh[4];
#pragma unroll
    for (int k = 0; k < 4; ++k) {
        hx[k] = ((const float4*)h0s)[lane + (k << 6)];
        hh[k] = ((const float4*)(ws + WS_H1 + p * H))[lane + (k << 6)];
    }
    {
        const int cell = (b << 2) + (w >> 1);
        const int r0 = cell + ((w & 1) << 11);
        const int r1 = r0 + 1024;
        float a0 = dot_row((const float4*)(Wih1 + (size_t)r0 * H), hx, lane)
                 + dot_row((const float4*)(Whh1 + (size_t)r0 * H), hh, lane);
        float a1 = dot_row((const float4*)(Wih1 + (size_t)r1 * H), hx, lane)
                 + dot_row((const float4*)(Whh1 + (size_t)r1 * H), hh, lane);
        a0 = wred(a0); a1 = wred(a1);
        if (lane == 0) {
            int gi = (w & 1) << 1;
            gl[w >> 1][gi]     = a0 + bih1[r0] + bhh1[r0];
            gl[w >> 1][gi + 1] = a1 + bih1[r1] + bhh1[r1];
        }
    }
    {
        const int g0r = (b << 4) + (w << 1);   // 16 G0 rows per block, 2 per wave
        float b0 = dot_row((const float4*)(Whh0 + (size_t)g0r * H), hx, lane);
        float b1 = dot_row((const float4*)(Whh0 + (size_t)(g0r + 1) * H), hx, lane);
        b0 = wred(b0); b1 = wred(b1);
        if (lane == 0) {
            ws[WS_G0 + (p ^ 1) * 4096 + g0r]     = b0 + bih0[g0r] + bhh0[g0r];
            ws[WS_G0 + (p ^ 1) * 4096 + g0r + 1] = b1 + bih0[g0r + 1] + bhh0[g0r + 1];
        }
    }
    __syncthreads();
    if (t < 4) {
        int cell = (b << 2) + t;
        float ig = sigmoidf_(gl[t][0]);
        float fg = sigmoidf_(gl[t][1]);
        float gg = tanhf(gl[t][2]);
        float og = sigmoidf_(gl[t][3]);
        float cc = fg * ws[WS_C1 + cell] + ig * gg;
        ws[WS_C1 + cell] = cc;
        ws[WS_H1 + (p ^ 1) * H + cell] = og * tanhf(cc);
    }
}

// ---- logits: relu(Wout@h1+bout) -> out row ; per-block (max, argmax) only ----
__global__ __launch_bounds__(256) void k_logits(const float* __restrict__ Wout,
                                                const float* __restrict__ bout,
                                                float* __restrict__ outrow,
                                                float* __restrict__ ws, int par) {
    __shared__ float pm[4];
    __shared__ int   pix[4];
    int b = blockIdx.x, t = threadIdx.x;
    int w = t >> 6, lane = t & 63;
    float4 hreg[4];
#pragma unroll
    for (int k = 0; k < 4; ++k)
        hreg[k] = ((const float4*)(ws + WS_H1 + par * H))[lane + (k << 6)];
    float m = -1e30f;
    int mi = 0x7fffffff;
    const int rbase = b * LROWS + (w << 2);
#pragma unroll
    for (int rr = 0; rr < 4; rr += 2) {
        int r = rbase + rr;
        float a0 = dot_row((const float4*)(Wout + (size_t)r * H), hreg, lane);
        float a1 = dot_row((const float4*)(Wout + (size_t)(r + 1) * H), hreg, lane);
        a0 = wred(a0); a1 = wred(a1);
        if (lane == 0) {
            float v0 = fmaxf(a0 + bout[r], 0.f);
            float v1 = fmaxf(a1 + bout[r + 1], 0.f);
            outrow[r] = v0; outrow[r + 1] = v1;
            if (v0 > m) { m = v0; mi = r; }
            if (v1 > m) { m = v1; mi = r + 1; }
        }
    }
    if (lane == 0) { pm[w] = m; pix[w] = mi; }
    __syncthreads();
    if (t == 0) {
        float bm = pm[0]; int bi = pix[0];
#pragma unroll
        for (int k = 1; k < 4; ++k) {
            if (pm[k] > bm) { bm = pm[k]; bi = pix[k]; }
            else if (pm[k] == bm && pix[k] < bi) bi = pix[k];
        }
        ws[WS_PMAX + b] = bm;
        ((int*)ws)[WS_PIDX + b] = bi;
    }
}

// ---- final: per-row logsumexp from stored logits, subtract ----
__global__ __launch_bounds__(1024) void k_final(float* __restrict__ out) {
    __shared__ float rm[1024], rs[1024];
    int s = blockIdx.x, t = threadIdx.x;   // 128 blocks, one row each
    float* row = out + (size_t)s * V;
    float m = -1e30f, sum = 0.f;
    for (int i = t; i < V; i += 1024) {
        float v = row[i];
        if (v > m) { sum = sum * expf(m - v) + 1.f; m = v; }
        else         sum += expf(v - m);
    }
    rm[t] = m; rs[t] = sum;
    __syncthreads();
    for (int o = 512; o > 0; o >>= 1) {
        if (t < o) {
            float m2 = rm[t + o], s2 = rs[t + o];
            if (m2 > rm[t]) { rs[t] = rs[t] * expf(rm[t] - m2) + s2; rm[t] = m2; }
            else              rs[t] += s2 * expf(m2 - rm[t]);
        }
        __syncthreads();
    }
    float logz = rm[0] + logf(rs[0]);
    for (int i = t; i < V; i += 1024) row[i] -= logz;
}

extern "C" void kernel_launch(void* const* d_in, const int* in_sizes, int n_in,
                              void* d_out, int out_size, void* d_ws, size_t ws_size,
                              hipStream_t stream) {
    const int*   y    = (const int*)d_in[0];
    const float* cv   = (const float*)d_in[1];
    const float* Wup  = (const float*)d_in[3];
    const float* bup  = (const float*)d_in[4];
    const float* Wih0 = (const float*)d_in[5];   // [4096,1] column
    const float* Whh0 = (const float*)d_in[6];
    const float* bih0 = (const float*)d_in[7];
    const float* bhh0 = (const float*)d_in[8];
    const float* Wih1 = (const float*)d_in[9];
    const float* Whh1 = (const float*)d_in[10];
    const float* bih1 = (const float*)d_in[11];
    const float* bhh1 = (const float*)d_in[12];
    const float* Wout = (const float*)d_in[13];
    const float* bout = (const float*)d_in[14];
    float* out = (float*)d_out;
    float* ws  = (float*)d_ws;

    k_setup<<<1024, 256, 0, stream>>>(Wup, bup, cv, ws);
    k_g0<<<1024, 256, 0, stream>>>(Whh0, bih0, bhh0, ws);
    for (int t = 0; t < NSTEP; ++t) {
        k_L<<<NBLK_L, NTHR_L, 0, stream>>>(y, Wih0, Whh0, bih0, bhh0,
                                           Wih1, Whh1, bih1, bhh1, ws, t);
        k_logits<<<LBLK, 256, 0, stream>>>(Wout, bout, out + (size_t)t * V, ws, (t & 1) ^ 1);
    }
    k_final<<<NSTEP, 1024, 0, stream>>>(out);
}

// Round 13
// 4762.582 us; speedup vs baseline: 2.8940x; 1.0113x over previous
//
#include <hip/hip_runtime.h>

#define H 1024
#define V 32000
#define NSTEP 128
#define LBLK 1000        // logits blocks
#define LROWS 32         // rows per logits block
#define LTHR 512
#define NBLK_L 256       // fused LSTM kernel blocks
#define NTHR_L 512

// ws float offsets
#define WS_G0    0        // [2][4096]  gate preact (Whh0@h0 + bih0 + bhh0), parity
#define WS_HINIT 8192     // [1024]
#define WS_C0    9216     // [2][1024]  parity
#define WS_H1    11264    // [2][1024]  parity
#define WS_C1    13312    // [1024]     block-owned
#define WS_PMAX  14336    // [LBLK]
#define WS_PIDX  16384    // [LBLK] (int)

__device__ __forceinline__ float sigmoidf_(float x) { return 1.f / (1.f + expf(-x)); }

__device__ __forceinline__ float wred(float a) {
#pragma unroll
    for (int o = 32; o > 0; o >>= 1) a += __shfl_down(a, o, 64);
    return a;   // valid in lane 0
}

// dot of one 1024-elem weight row with vector held in 4 float4 regs (lane-sliced)
__device__ __forceinline__ float dot_row(const float4* __restrict__ w4,
                                         const float4* h, int lane) {
    float a = 0.f;
#pragma unroll
    for (int k = 0; k < 4; ++k) {
        float4 w = w4[lane + (k << 6)];
        a += w.x * h[k].x + w.y * h[k].y + w.z * h[k].z + w.w * h[k].w;
    }
    return a;
}

// ---- setup: h_init = Wup @ (cv0*cv1) + bup ; init state ----
__global__ __launch_bounds__(256) void k_setup(const float* __restrict__ Wup,
                                               const float* __restrict__ bup,
                                               const float* __restrict__ cv,
                                               float* __restrict__ ws) {
    int r = blockIdx.x, t = threadIdx.x;   // 1024 blocks
    __shared__ float red[256];
    const float* row = Wup + (size_t)r * H;
    float acc = 0.f;
    for (int j = t; j < H; j += 256) acc += row[j] * (cv[j] * cv[H + j]);
    red[t] = acc;
    __syncthreads();
    for (int s = 128; s > 0; s >>= 1) { if (t < s) red[t] += red[t + s]; __syncthreads(); }
    if (t == 0) {
        float h = red[0] + bup[r];
        ws[WS_HINIT + r] = h;
        ws[WS_C0 + r] = h;       // parity 0
        ws[WS_H1 + r] = h;       // parity 0
        ws[WS_C1 + r] = h;
    }
}

// ---- G0(0) = Whh0 @ h_init + bih0 + bhh0 ----
__global__ __launch_bounds__(256) void k_g0(const float* __restrict__ Whh0,
                                            const float* __restrict__ bih0,
                                            const float* __restrict__ bhh0,
                                            float* __restrict__ ws) {
    int b = blockIdx.x, t = threadIdx.x;   // 1024 blocks, 4 waves, 1 row/wave
    int w = t >> 6, lane = t & 63;
    float4 hreg[4];
#pragma unroll
    for (int k = 0; k < 4; ++k) hreg[k] = ((const float4*)(ws + WS_HINIT))[lane + (k << 6)];
    int r = (b << 2) + w;
    float a = wred(dot_row((const float4*)(Whh0 + (size_t)r * H), hreg, lane));
    if (lane == 0) ws[WS_G0 + r] = a + bih0[r] + bhh0[r];   // parity 0
}

// ---- fused: argmax(prev partials) -> tok ; lstm0-finish (redundant) ;
//      lstm1 matvec (4 cells/block) ; G0(next) rows ----
__global__ __launch_bounds__(NTHR_L) void k_L(
    const int* __restrict__ y,
    const float* __restrict__ Wih0col,
    const float* __restrict__ Whh0,
    const float* __restrict__ bih0, const float* __restrict__ bhh0,
    const float* __restrict__ Wih1, const float* __restrict__ Whh1,
    const float* __restrict__ bih1, const float* __restrict__ bhh1,
    float* __restrict__ ws, int step)
{
    const int b = blockIdx.x, t = threadIdx.x;
    const int w = t >> 6, lane = t & 63;
    const int p = step & 1;
    __shared__ float h0s[H];
    __shared__ float rm[NTHR_L];
    __shared__ int   ri[NTHR_L];
    __shared__ float gl[4][4];

    // ---- phase 1a: token from prev-step partials (redundant per block) ----
    float tok;
    if (step == 0) {
        tok = (float)y[0];
    } else {
        float m = -1e30f;
        int idx = 0x7fffffff;
        for (int i = t; i < LBLK; i += NTHR_L) {
            float m2 = ws[WS_PMAX + i];
            int i2 = ((const int*)ws)[WS_PIDX + i];
            if (m2 > m) { m = m2; idx = i2; }
            else if (m2 == m && i2 < idx) idx = i2;
        }
        rm[t] = m; ri[t] = idx;
        __syncthreads();
        for (int o = NTHR_L >> 1; o > 0; o >>= 1) {
            if (t < o) {
                float m2 = rm[t + o]; int i2 = ri[t + o];
                if (m2 > rm[t]) { rm[t] = m2; ri[t] = i2; }
                else if (m2 == rm[t] && i2 < ri[t]) ri[t] = i2;
            }
            __syncthreads();
        }
        tok = (float)ri[0];
    }

    // ---- phase 1b: finish lstm0 redundantly; h0_new -> LDS; c0 parity flip ----
    for (int c = t; c < H; c += NTHR_L) {
        float gi = ws[WS_G0 + p * 4096 + c]        + Wih0col[c]        * tok;
        float gf = ws[WS_G0 + p * 4096 + 1024 + c] + Wih0col[1024 + c] * tok;
        float gg = ws[WS_G0 + p * 4096 + 2048 + c] + Wih0col[2048 + c] * tok;
        float go = ws[WS_G0 + p * 4096 + 3072 + c] + Wih0col[3072 + c] * tok;
        float cc = sigmoidf_(gf) * ws[WS_C0 + p * H + c] + sigmoidf_(gi) * tanhf(gg);
        ws[WS_C0 + (p ^ 1) * H + c] = cc;          // identical values from all blocks
        h0s[c] = sigmoidf_(go) * tanhf(cc);
    }
    __syncthreads();

    // ---- phase 2: lstm1 matvec + G0(next) ----
    float4 hx[4], hh[4];
#pragma unroll
    for (int k = 0; k < 4; ++k) {
        hx[k] = ((const float4*)h0s)[lane + (k << 6)];
        hh[k] = ((const float4*)(ws + WS_H1 + p * H))[lane + (k << 6)];
    }
    {
        const int cell = (b << 2) + (w >> 1);
        const int r0 = cell + ((w & 1) << 11);
        const int r1 = r0 + 1024;
        float a0 = dot_row((const float4*)(Wih1 + (size_t)r0 * H), hx, lane)
                 + dot_row((const float4*)(Whh1 + (size_t)r0 * H), hh, lane);
        float a1 = dot_row((const float4*)(Wih1 + (size_t)r1 * H), hx, lane)
                 + dot_row((const float4*)(Whh1 + (size_t)r1 * H), hh, lane);
        a0 = wred(a0); a1 = wred(a1);
        if (lane == 0) {
            int gi = (w & 1) << 1;
            gl[w >> 1][gi]     = a0 + bih1[r0] + bhh1[r0];
            gl[w >> 1][gi + 1] = a1 + bih1[r1] + bhh1[r1];
        }
    }
    {
        const int g0r = (b << 4) + (w << 1);   // 16 G0 rows per block, 2 per wave
        float b0 = dot_row((const float4*)(Whh0 + (size_t)g0r * H), hx, lane);
        float b1 = dot_row((const float4*)(Whh0 + (size_t)(g0r + 1) * H), hx, lane);
        b0 = wred(b0); b1 = wred(b1);
        if (lane == 0) {
            ws[WS_G0 + (p ^ 1) * 4096 + g0r]     = b0 + bih0[g0r] + bhh0[g0r];
            ws[WS_G0 + (p ^ 1) * 4096 + g0r + 1] = b1 + bih0[g0r + 1] + bhh0[g0r + 1];
        }
    }
    __syncthreads();
    if (t < 4) {
        int cell = (b << 2) + t;
        float ig = sigmoidf_(gl[t][0]);
        float fg = sigmoidf_(gl[t][1]);
        float gg = tanhf(gl[t][2]);
        float og = sigmoidf_(gl[t][3]);
        float cc = fg * ws[WS_C1 + cell] + ig * gg;
        ws[WS_C1 + cell] = cc;
        ws[WS_H1 + (p ^ 1) * H + cell] = og * tanhf(cc);
    }
}

// ---- logits: relu(Wout@h1+bout) -> out row ; per-block (max, argmax) only ----
__global__ __launch_bounds__(LTHR) void k_logits(const float* __restrict__ Wout,
                                                 const float* __restrict__ bout,
                                                 float* __restrict__ outrow,
                                                 float* __restrict__ ws, int par) {
    __shared__ float pm[8];
    __shared__ int   pix[8];
    int b = blockIdx.x, t = threadIdx.x;
    int w = t >> 6, lane = t & 63;      // 8 waves
    float4 hreg[4];
#pragma unroll
    for (int k = 0; k < 4; ++k)
        hreg[k] = ((const float4*)(ws + WS_H1 + par * H))[lane + (k << 6)];
    float m = -1e30f;
    int mi = 0x7fffffff;
    const int rbase = b * LROWS + (w << 2);   // 4 rows per wave
#pragma unroll
    for (int rr = 0; rr < 4; rr += 2) {
        int r = rbase + rr;
        float a0 = dot_row((const float4*)(Wout + (size_t)r * H), hreg, lane);
        float a1 = dot_row((const float4*)(Wout + (size_t)(r + 1) * H), hreg, lane);
        a0 = wred(a0); a1 = wred(a1);
        if (lane == 0) {
            float v0 = fmaxf(a0 + bout[r], 0.f);
            float v1 = fmaxf(a1 + bout[r + 1], 0.f);
            outrow[r] = v0; outrow[r + 1] = v1;
            if (v0 > m) { m = v0; mi = r; }
            if (v1 > m) { m = v1; mi = r + 1; }
        }
    }
    if (lane == 0) { pm[w] = m; pix[w] = mi; }
    __syncthreads();
    if (t == 0) {
        float bm = pm[0]; int bi = pix[0];
#pragma unroll
        for (int k = 1; k < 8; ++k) {
            if (pm[k] > bm) { bm = pm[k]; bi = pix[k]; }
            else if (pm[k] == bm && pix[k] < bi) bi = pix[k];
        }
        ws[WS_PMAX + b] = bm;
        ((int*)ws)[WS_PIDX + b] = bi;
    }
}

// ---- final: per-row logsumexp from stored logits, subtract ----
__global__ __launch_bounds__(1024) void k_final(float* __restrict__ out) {
    __shared__ float rm[1024], rs[1024];
    int s = blockIdx.x, t = threadIdx.x;   // 128 blocks, one row each
    float* row = out + (size_t)s * V;
    float m = -1e30f, sum = 0.f;
    for (int i = t; i < V; i += 1024) {
        float v = row[i];
        if (v > m) { sum = sum * expf(m - v) + 1.f; m = v; }
        else         sum += expf(v - m);
    }
    rm[t] = m; rs[t] = sum;
    __syncthreads();
    for (int o = 512; o > 0; o >>= 1) {
        if (t < o) {
            float m2 = rm[t + o], s2 = rs[t + o];
            if (m2 > rm[t]) { rs[t] = rs[t] * expf(rm[t] - m2) + s2; rm[t] = m2; }
            else              rs[t] += s2 * expf(m2 - rm[t]);
        }
        __syncthreads();
    }
    float logz = rm[0] + logf(rs[0]);
    for (int i = t; i < V; i += 1024) row[i] -= logz;
}

extern "C" void kernel_launch(void* const* d_in, const int* in_sizes, int n_in,
                              void* d_out, int out_size, void* d_ws, size_t ws_size,
                              hipStream_t stream) {
    const int*   y    = (const int*)d_in[0];
    const float* cv   = (const float*)d_in[1];
    const float* Wup  = (const float*)d_in[3];
    const float* bup  = (const float*)d_in[4];
    const float* Wih0 = (const float*)d_in[5];   // [4096,1] column
    const float* Whh0 = (const float*)d_in[6];
    const float* bih0 = (const float*)d_in[7];
    const float* bhh0 = (const float*)d_in[8];
    const float* Wih1 = (const float*)d_in[9];
    const float* Whh1 = (const float*)d_in[10];
    const float* bih1 = (const float*)d_in[11];
    const float* bhh1 = (const float*)d_in[12];
    const float* Wout = (const float*)d_in[13];
    const float* bout = (const float*)d_in[14];
    float* out = (float*)d_out;
    float* ws  = (float*)d_ws;

    k_setup<<<1024, 256, 0, stream>>>(Wup, bup, cv, ws);
    k_g0<<<1024, 256, 0, stream>>>(Whh0, bih0, bhh0, ws);
    for (int t = 0; t < NSTEP; ++t) {
        k_L<<<NBLK_L, NTHR_L, 0, stream>>>(y, Wih0, Whh0, bih0, bhh0,
                                           Wih1, Whh1, bih1, bhh1, ws, t);
        k_logits<<<LBLK, LTHR, 0, stream>>>(Wout, bout, out + (size_t)t * V, ws, (t & 1) ^ 1);
    }
    k_final<<<NSTEP, 1024, 0, stream>>>(out);
}